// Round 6
// baseline (323.003 us; speedup 1.0000x reference)
//
#include <hip/hip_runtime.h>
#include <hip/hip_bf16.h>
#include <hip/hip_cooperative_groups.h>

namespace cg = cooperative_groups;

#define N_TOT   32768
#define NUMNODE 128
#define NGRAPH  256
#define EDGES   524288
#define HDIM    128
#define MLP_HID 512
#define OUTDIM  10
#define KBIG    16384   // NUMNODE*HDIM
#define KSLICES 32      // lin1 split-K slices

typedef __attribute__((ext_vector_type(8))) short  short8;   // 8 x bf16 bits
typedef __attribute__((ext_vector_type(4))) float  floatx4;  // MFMA accumulator
typedef unsigned short u16;
typedef unsigned int   u32;

#define MFMA(a,b,c) __builtin_amdgcn_mfma_f32_16x16x32_bf16((a),(b),(c),0,0,0)

__device__ __forceinline__ u16 f2b(float f){
  union { __hip_bfloat16 h; u16 u; } cv; cv.h = __float2bfloat16(f); return cv.u;
}

// ==== single cooperative kernel: GNN -> lin1 -> lin2 ====
// 256 blocks x 512 threads, 64 KB LDS, 1 block/CU (co-resident by capacity).
// Phase A: per-graph fused GCN (adjacency from LDS counts; layer2 via
//          associativity (A@h1act)@W2) -> hact[256][16384] bf16.
// Phase B: lin1 partials, virtual grid 8(n) x 32(kslice), BK-span 512/block.
// Phase C: per-graph slice-reduce + b1 + relu + lin2 -> out.
__global__ __launch_bounds__(512) void k_fused(
    const float* __restrict__ x, const int* __restrict__ ei,
    const float* __restrict__ W1, const float* __restrict__ b1,
    const float* __restrict__ W2, const float* __restrict__ b2,
    const float* __restrict__ l1w, const float* __restrict__ l1b,
    const float* __restrict__ l2w, const float* __restrict__ l2b,
    u16* __restrict__ hact, float* __restrict__ P, float* __restrict__ out)
{
  __shared__ char smem[65536];
  cg::grid_group grid = cg::this_grid();
  int t = threadIdx.x;
  int wave = t>>6, lane = t&63, r = lane&15, q = lane>>4;

  // ================= Phase A: per-graph GNN =================
  {
    u32*   adjC  = (u32*)smem;                // [128][64] packed u16 counts
    u16*   adjB  = (u16*)smem;                // [128][128] bf16 swizzled
    u16*   WL    = (u16*)smem;                // w2T home (after P5)
    float* dinvF = (float*)smem;              // 128 floats (transient)
    u16*   R1    = (u16*)(smem + 32768);      // w1T / hT / h1T / amid / out
    int g = blockIdx.x;
    int m0 = wave*16;

    // P0: zero lower 32 KB; stage w1T (transposed bf16, swizzled) into upper
    #pragma unroll
    for (int i=0;i<4;++i) ((int4*)smem)[t + i*512] = make_int4(0,0,0,0);
    #pragma unroll
    for (int rep=0;rep<32;++rep){
      int idx = rep*512 + t;                  // = k*128 + n (W1 flat)
      int n = idx & 127, k = idx >> 7;
      R1[n*128 + (((k>>3) ^ (n&7)))*8 + (k&7)] = f2b(W1[idx]);
    }
    __syncthreads();

    // P1: scatter edge counts, packed 2 per u32
    #pragma unroll
    for (int k=0;k<4;++k){
      int e = g*2048 + k*512 + t;
      int s = ei[e] & 127;
      int d = ei[EDGES + e] & 127;
      atomicAdd(&adjC[d*64 + (s>>1)], 1u << (16*(s&1)));
    }
    __syncthreads();

    // P2a: own quarter-row counts -> regs; rowsum via shfl -> dinv
    int drow = t >> 2, c0q = (t & 3)*16, scol = (t & 3)*32;
    u32 cnts[16];
    float dinv_own;
    {
      u32 sum = 0;
      #pragma unroll
      for (int i=0;i<16;++i){
        cnts[i] = adjC[drow*64 + c0q + i];
        sum += (cnts[i] & 0xffffu) + (cnts[i] >> 16);
      }
      sum += __shfl_xor((int)sum, 1);
      sum += __shfl_xor((int)sum, 2);
      dinv_own = rsqrtf((float)sum + 1.0f);
    }
    __syncthreads();
    if ((t & 3) == 0) dinvF[drow] = dinv_own;
    __syncthreads();
    float vdst = dinvF[drow];
    float ds[32];
    #pragma unroll
    for (int i=0;i<8;++i)
      ((float4*)ds)[i] = *(const float4*)(dinvF + scol + i*4);
    __syncthreads();
    // P2d: normalize + self-loop diag, write adjB swizzled
    {
      float vals[32];
      #pragma unroll
      for (int i=0;i<16;++i){
        vals[2*i]   = (float)(cnts[i] & 0xffffu) * vdst * ds[2*i];
        vals[2*i+1] = (float)(cnts[i] >> 16)     * vdst * ds[2*i+1];
      }
      #pragma unroll
      for (int i=0;i<32;++i) if (drow == scol + i) vals[i] += vdst*vdst;
      #pragma unroll
      for (int cc=0;cc<4;++cc){
        int ch  = (scol >> 3) + cc;
        short8 o;
        #pragma unroll
        for (int j=0;j<8;++j) o[j] = (short)f2b(vals[cc*8 + j]);
        *(short8*)(adjB + drow*128 + (ch ^ (drow&7))*8) = o;
      }
    }
    // no barrier needed before P3 (P3 touches only upper LDS + global)

    // P3: GEMM1  h1 = x @ W1 -> hT [f][node] swizzled upper
    floatx4 acc[8];
    #pragma unroll
    for (int i=0;i<8;++i) acc[i] = (floatx4){0.f,0.f,0.f,0.f};
    {
      const float* xg = x + ((size_t)(g*128 + m0 + r))*HDIM;
      #pragma unroll
      for (int ks=0;ks<4;++ks){
        float4 a0 = *(const float4*)(xg + ks*32 + q*8);
        float4 a1 = *(const float4*)(xg + ks*32 + q*8 + 4);
        short8 af;
        af[0]=(short)f2b(a0.x); af[1]=(short)f2b(a0.y); af[2]=(short)f2b(a0.z); af[3]=(short)f2b(a0.w);
        af[4]=(short)f2b(a1.x); af[5]=(short)f2b(a1.y); af[6]=(short)f2b(a1.z); af[7]=(short)f2b(a1.w);
        #pragma unroll
        for (int nt=0;nt<8;++nt){
          short8 bf = *(const short8*)(R1 + (nt*16+r)*128 + (((ks*4+q) ^ (r&7)))*8);
          acc[nt] = MFMA(af, bf, acc[nt]);
        }
      }
    }
    __syncthreads();                          // w1T reads done; adjB writes done
    #pragma unroll
    for (int nt=0;nt<8;++nt){
      int f = nt*16 + r;
      int c = 2*wave + (q>>1);
      ushort4 o; o.x=f2b(acc[nt][0]); o.y=f2b(acc[nt][1]); o.z=f2b(acc[nt][2]); o.w=f2b(acc[nt][3]);
      *(ushort4*)(R1 + f*128 + (c ^ (f&7))*8 + (q&1)*4) = o;
    }
    __syncthreads();

    // P4: agg1 = adj @ h1 (+b1, relu) -> h1T [f][node] upper
    #pragma unroll
    for (int i=0;i<8;++i) acc[i] = (floatx4){0.f,0.f,0.f,0.f};
    #pragma unroll
    for (int ks=0;ks<4;++ks){
      int ca = ks*4 + q;
      short8 af = *(const short8*)(adjB + (m0+r)*128 + ((ca ^ (r&7)))*8);
      #pragma unroll
      for (int nt=0;nt<8;++nt){
        short8 bf = *(const short8*)(R1 + (nt*16+r)*128 + ((ca ^ (r&7)))*8);
        acc[nt] = MFMA(af, bf, acc[nt]);
      }
    }
    {
      ushort4 ho[8];
      #pragma unroll
      for (int nt=0;nt<8;++nt){
        float bb = b1[nt*16 + r];
        ho[nt].x = f2b(fmaxf(acc[nt][0] + bb, 0.f));
        ho[nt].y = f2b(fmaxf(acc[nt][1] + bb, 0.f));
        ho[nt].z = f2b(fmaxf(acc[nt][2] + bb, 0.f));
        ho[nt].w = f2b(fmaxf(acc[nt][3] + bb, 0.f));
      }
      __syncthreads();                        // hT reads done
      #pragma unroll
      for (int nt=0;nt<8;++nt){
        int f = nt*16 + r;
        int c = 2*wave + (q>>1);
        *(ushort4*)(R1 + f*128 + (c ^ (f&7))*8 + (q&1)*4) = ho[nt];
      }
    }
    __syncthreads();

    // P5: amid = adj @ h1act -> [d][f] swizzled upper; stage w2T lower
    #pragma unroll
    for (int i=0;i<8;++i) acc[i] = (floatx4){0.f,0.f,0.f,0.f};
    #pragma unroll
    for (int ks=0;ks<4;++ks){
      int ca = ks*4 + q;
      short8 af = *(const short8*)(adjB + (m0+r)*128 + ((ca ^ (r&7)))*8);
      #pragma unroll
      for (int nt=0;nt<8;++nt){
        short8 bf = *(const short8*)(R1 + (nt*16+r)*128 + ((ca ^ (r&7)))*8);
        acc[nt] = MFMA(af, bf, acc[nt]);
      }
    }
    {
      u16 hv[32];
      #pragma unroll
      for (int nt=0;nt<8;++nt)
        #pragma unroll
        for (int rr=0;rr<4;++rr) hv[nt*4+rr] = f2b(acc[nt][rr]);
      __syncthreads();                        // adjB + h1T reads done
      #pragma unroll
      for (int rep=0;rep<32;++rep){           // w2T -> lower (overwrite adjB)
        int idx = rep*512 + t;
        int n = idx & 127, k = idx >> 7;
        WL[n*128 + (((k>>3) ^ (n&7)))*8 + (k&7)] = f2b(W2[idx]);
      }
      #pragma unroll
      for (int nt=0;nt<8;++nt){
        int ch = 2*nt + (r>>3);
        #pragma unroll
        for (int rr=0;rr<4;++rr){
          int d = m0 + q*4 + rr;
          R1[d*128 + (ch ^ (d&7))*8 + (r&7)] = hv[nt*4+rr];
        }
      }
    }
    __syncthreads();

    // P6: h2 = relu(amid @ W2 + b2) -> [d][f] -> hact
    #pragma unroll
    for (int i=0;i<8;++i) acc[i] = (floatx4){0.f,0.f,0.f,0.f};
    #pragma unroll
    for (int ks=0;ks<4;++ks){
      int ca = ks*4 + q;
      short8 af = *(const short8*)(R1 + (m0+r)*128 + ((ca ^ (r&7)))*8);
      #pragma unroll
      for (int nt=0;nt<8;++nt){
        short8 bf = *(const short8*)(WL + (nt*16+r)*128 + ((ca ^ (r&7)))*8);
        acc[nt] = MFMA(af, bf, acc[nt]);
      }
    }
    {
      u16 hv[32];
      #pragma unroll
      for (int nt=0;nt<8;++nt){
        float bb = b2[nt*16 + r];
        #pragma unroll
        for (int rr=0;rr<4;++rr) hv[nt*4+rr] = f2b(fmaxf(acc[nt][rr] + bb, 0.f));
      }
      __syncthreads();                        // amid reads done
      #pragma unroll
      for (int nt=0;nt<8;++nt){
        int f = nt*16 + r;
        #pragma unroll
        for (int rr=0;rr<4;++rr){
          int d = m0 + q*4 + rr;
          R1[d*128 + f] = hv[nt*4+rr];        // linear for vectorized copy-out
        }
      }
    }
    __syncthreads();
    u16* hg = hact + (size_t)g*KBIG;
    #pragma unroll
    for (int i=0;i<4;++i) ((int4*)hg)[t + i*512] = ((const int4*)R1)[t + i*512];
  }

  __threadfence();
  grid.sync();

  // ================= Phase B: lin1 partials =================
  // virtual block: n0 = (b&7)*64, kslice = b>>3 (K-span 512), BK=64 x 8 iters
  {
    u16* Al = (u16*)smem;            // [256][64] u16, 8 chunks XOR-swizzled (32 KB)
    u16* Bl = (u16*)(smem + 32768);  // [64][64]  u16, swizzled (8 KB)
    int vb = blockIdx.x;
    int n0 = (vb & 7)*64;
    int kbase = (vb >> 3)*512;
    floatx4 acc[2][4];
    #pragma unroll
    for (int i=0;i<2;++i)
      #pragma unroll
      for (int j=0;j<4;++j) acc[i][j] = (floatx4){0.f,0.f,0.f,0.f};

    for (int it=0; it<8; ++it){
      __syncthreads();
      int kk = kbase + it*64;
      #pragma unroll
      for (int p=0;p<4;++p){                  // A: 256 rows x 64 k
        int idx = p*512 + t;
        int row = idx >> 3, ch = idx & 7;
        int4 va = *(const int4*)(hact + (size_t)row*KBIG + kk + ch*8);
        *(int4*)(Al + row*64 + ((ch ^ (row&7)))*8) = va;
      }
      #pragma unroll
      for (int h=0;h<2;++h){                  // B: l1w[kk..kk+63][n0..n0+63] -> Bl[n][k]
        int i = h*512 + t;
        int k = i >> 4, n4 = i & 15;
        float4 w = *(const float4*)(l1w + (size_t)(kk + k)*MLP_HID + n0 + n4*4);
        #pragma unroll
        for (int j=0;j<4;++j){
          int n = n4*4 + j;
          Bl[n*64 + (((k>>3) ^ (n&7)))*8 + (k&7)] = f2b(j==0?w.x:j==1?w.y:j==2?w.z:w.w);
        }
      }
      __syncthreads();
      #pragma unroll
      for (int ks=0;ks<2;++ks){
        int ca = ks*4 + q;
        short8 a0 = *(const short8*)(Al + (wave*32      + r)*64 + ((ca ^ (r&7)))*8);
        short8 a1 = *(const short8*)(Al + (wave*32 + 16 + r)*64 + ((ca ^ (r&7)))*8);
        #pragma unroll
        for (int nt=0;nt<4;++nt){
          short8 b = *(const short8*)(Bl + (nt*16+r)*64 + ((ca ^ (r&7)))*8);
          acc[0][nt] = MFMA(a0, b, acc[0][nt]);
          acc[1][nt] = MFMA(a1, b, acc[1][nt]);
        }
      }
    }
    float* Pp = P + (size_t)(vb >> 3)*131072;
    #pragma unroll
    for (int mm=0;mm<2;++mm)
      #pragma unroll
      for (int nt=0;nt<4;++nt)
        #pragma unroll
        for (int rr=0;rr<4;++rr)
          Pp[(size_t)(wave*32 + mm*16 + q*4 + rr)*MLP_HID + n0 + nt*16 + r] = acc[mm][nt][rr];
  }

  __threadfence();
  grid.sync();

  // ================= Phase C: reduce + relu + lin2 =================
  {
    float* hs = (float*)smem;        // 512 floats
    int g = blockIdx.x;
    float s = l1b[t];
    #pragma unroll 8
    for (int sl=0;sl<KSLICES;++sl) s += P[(size_t)sl*131072 + (size_t)g*MLP_HID + t];
    __syncthreads();                 // phase B LDS reads done (any wave)
    hs[t] = fmaxf(s, 0.f);
    __syncthreads();
    for (int j = wave; j < OUTDIM; j += 8){
      float p = 0.f;
      #pragma unroll
      for (int i=0;i<8;++i) p += hs[lane + i*64] * l2w[(lane + i*64)*OUTDIM + j];
      #pragma unroll
      for (int off=32; off>0; off>>=1) p += __shfl_down(p, off);
      if (lane == 0) out[g*OUTDIM + j] = p + l2b[j];
    }
  }
}

extern "C" void kernel_launch(void* const* d_in, const int* in_sizes, int n_in,
                              void* d_out, int out_size, void* d_ws, size_t ws_size,
                              hipStream_t stream){
  const float* x   = (const float*)d_in[0];
  const int*   ei  = (const int*)d_in[1];
  const float* W1  = (const float*)d_in[3];
  const float* b1  = (const float*)d_in[4];
  const float* W2  = (const float*)d_in[5];
  const float* b2  = (const float*)d_in[6];
  const float* l1w = (const float*)d_in[7];
  const float* l1b = (const float*)d_in[8];
  const float* l2w = (const float*)d_in[9];
  const float* l2b = (const float*)d_in[10];
  float* out = (float*)d_out;

  char* ws = (char*)d_ws;
  u16*   hact = (u16*)  (ws + 0);          // 8 MB
  float* P    = (float*)(ws + 8388608);    // 16 MB partials (fully overwritten)

  void* args[] = {
    (void*)&x, (void*)&ei, (void*)&W1, (void*)&b1, (void*)&W2, (void*)&b2,
    (void*)&l1w, (void*)&l1b, (void*)&l2w, (void*)&l2b,
    (void*)&hact, (void*)&P, (void*)&out
  };
  hipLaunchCooperativeKernel((const void*)k_fused, dim3(NGRAPH), dim3(512),
                             args, 0, stream);
}

// Round 7
// 149.086 us; speedup vs baseline: 2.1666x; 2.1666x over previous
//
#include <hip/hip_runtime.h>
#include <hip/hip_bf16.h>

#define N_TOT   32768
#define NUMNODE 128
#define NGRAPH  256
#define EDGES   524288
#define HDIM    128
#define MLP_HID 512
#define OUTDIM  10
#define KBIG    16384   // NUMNODE*HDIM
#define KSLICES 32      // lin1 split-K slices

typedef __attribute__((ext_vector_type(8))) short  short8;   // 8 x bf16 bits
typedef __attribute__((ext_vector_type(4))) float  floatx4;  // MFMA accumulator
typedef unsigned short u16;
typedef unsigned int   u32;

#define MFMA(a,b,c) __builtin_amdgcn_mfma_f32_16x16x32_bf16((a),(b),(c),0,0,0)

__device__ __forceinline__ u16 f2b(float f){
  union { __hip_bfloat16 h; u16 u; } cv; cv.h = __float2bfloat16(f); return cv.u;
}

// ==== fully self-contained per-graph GNN megakernel (same as R5) ====
__global__ __launch_bounds__(512) void k_gnn(
    const float* __restrict__ x, const int* __restrict__ ei,
    const float* __restrict__ W1, const float* __restrict__ W2,
    const float* __restrict__ b1, const float* __restrict__ b2,
    u16* __restrict__ hact)
{
  __shared__ char smem[65536];
  u32*   adjC  = (u32*)smem;                // [128][64] packed u16 counts
  u16*   adjB  = (u16*)smem;                // [128][128] bf16 swizzled
  u16*   WL    = (u16*)smem;                // w2T home (after P5)
  float* dinvF = (float*)smem;              // 128 floats (transient)
  u16*   R1    = (u16*)(smem + 32768);      // w1T / hT / h1T / amid / out
  int g = blockIdx.x, t = threadIdx.x;
  int wave = t>>6, lane = t&63, r = lane&15, q = lane>>4;
  int m0 = wave*16;

  // P0: zero lower 32 KB; stage w1T (transposed bf16, swizzled) into upper
  #pragma unroll
  for (int i=0;i<4;++i) ((int4*)smem)[t + i*512] = make_int4(0,0,0,0);
  #pragma unroll
  for (int rep=0;rep<32;++rep){
    int idx = rep*512 + t;                  // = k*128 + n (W1 flat)
    int n = idx & 127, k = idx >> 7;
    R1[n*128 + (((k>>3) ^ (n&7)))*8 + (k&7)] = f2b(W1[idx]);
  }
  __syncthreads();

  // P1: scatter edge counts, packed 2 per u32
  #pragma unroll
  for (int k=0;k<4;++k){
    int e = g*2048 + k*512 + t;
    int s = ei[e] & 127;
    int d = ei[EDGES + e] & 127;
    atomicAdd(&adjC[d*64 + (s>>1)], 1u << (16*(s&1)));
  }
  __syncthreads();

  // P2a: own quarter-row counts -> regs; rowsum via shfl -> dinv
  int drow = t >> 2, c0q = (t & 3)*16, scol = (t & 3)*32;
  u32 cnts[16];
  float dinv_own;
  {
    u32 sum = 0;
    #pragma unroll
    for (int i=0;i<16;++i){
      cnts[i] = adjC[drow*64 + c0q + i];
      sum += (cnts[i] & 0xffffu) + (cnts[i] >> 16);
    }
    sum += __shfl_xor((int)sum, 1);
    sum += __shfl_xor((int)sum, 2);
    dinv_own = rsqrtf((float)sum + 1.0f);
  }
  __syncthreads();
  if ((t & 3) == 0) dinvF[drow] = dinv_own;
  __syncthreads();
  float vdst = dinvF[drow];
  float ds[32];
  #pragma unroll
  for (int i=0;i<8;++i)
    ((float4*)ds)[i] = *(const float4*)(dinvF + scol + i*4);
  __syncthreads();
  // P2d: normalize + self-loop diag, write adjB swizzled
  {
    float vals[32];
    #pragma unroll
    for (int i=0;i<16;++i){
      vals[2*i]   = (float)(cnts[i] & 0xffffu) * vdst * ds[2*i];
      vals[2*i+1] = (float)(cnts[i] >> 16)     * vdst * ds[2*i+1];
    }
    #pragma unroll
    for (int i=0;i<32;++i) if (drow == scol + i) vals[i] += vdst*vdst;
    #pragma unroll
    for (int cc=0;cc<4;++cc){
      int ch  = (scol >> 3) + cc;
      short8 o;
      #pragma unroll
      for (int j=0;j<8;++j) o[j] = (short)f2b(vals[cc*8 + j]);
      *(short8*)(adjB + drow*128 + (ch ^ (drow&7))*8) = o;
    }
  }
  // no barrier needed before P3 (P3 touches only upper LDS + global)

  // P3: GEMM1  h1 = x @ W1 -> hT [f][node] swizzled upper
  floatx4 acc[8];
  #pragma unroll
  for (int i=0;i<8;++i) acc[i] = (floatx4){0.f,0.f,0.f,0.f};
  {
    const float* xg = x + ((size_t)(g*128 + m0 + r))*HDIM;
    #pragma unroll
    for (int ks=0;ks<4;++ks){
      float4 a0 = *(const float4*)(xg + ks*32 + q*8);
      float4 a1 = *(const float4*)(xg + ks*32 + q*8 + 4);
      short8 af;
      af[0]=(short)f2b(a0.x); af[1]=(short)f2b(a0.y); af[2]=(short)f2b(a0.z); af[3]=(short)f2b(a0.w);
      af[4]=(short)f2b(a1.x); af[5]=(short)f2b(a1.y); af[6]=(short)f2b(a1.z); af[7]=(short)f2b(a1.w);
      #pragma unroll
      for (int nt=0;nt<8;++nt){
        short8 bf = *(const short8*)(R1 + (nt*16+r)*128 + (((ks*4+q) ^ (r&7)))*8);
        acc[nt] = MFMA(af, bf, acc[nt]);
      }
    }
  }
  __syncthreads();                          // w1T reads done; adjB writes done
  #pragma unroll
  for (int nt=0;nt<8;++nt){
    int f = nt*16 + r;
    int c = 2*wave + (q>>1);
    ushort4 o; o.x=f2b(acc[nt][0]); o.y=f2b(acc[nt][1]); o.z=f2b(acc[nt][2]); o.w=f2b(acc[nt][3]);
    *(ushort4*)(R1 + f*128 + (c ^ (f&7))*8 + (q&1)*4) = o;
  }
  __syncthreads();

  // P4: agg1 = adj @ h1 (+b1, relu) -> h1T [f][node] upper
  #pragma unroll
  for (int i=0;i<8;++i) acc[i] = (floatx4){0.f,0.f,0.f,0.f};
  #pragma unroll
  for (int ks=0;ks<4;++ks){
    int ca = ks*4 + q;
    short8 af = *(const short8*)(adjB + (m0+r)*128 + ((ca ^ (r&7)))*8);
    #pragma unroll
    for (int nt=0;nt<8;++nt){
      short8 bf = *(const short8*)(R1 + (nt*16+r)*128 + ((ca ^ (r&7)))*8);
      acc[nt] = MFMA(af, bf, acc[nt]);
    }
  }
  {
    ushort4 ho[8];
    #pragma unroll
    for (int nt=0;nt<8;++nt){
      float bb = b1[nt*16 + r];
      ho[nt].x = f2b(fmaxf(acc[nt][0] + bb, 0.f));
      ho[nt].y = f2b(fmaxf(acc[nt][1] + bb, 0.f));
      ho[nt].z = f2b(fmaxf(acc[nt][2] + bb, 0.f));
      ho[nt].w = f2b(fmaxf(acc[nt][3] + bb, 0.f));
    }
    __syncthreads();                        // hT reads done
    #pragma unroll
    for (int nt=0;nt<8;++nt){
      int f = nt*16 + r;
      int c = 2*wave + (q>>1);
      *(ushort4*)(R1 + f*128 + (c ^ (f&7))*8 + (q&1)*4) = ho[nt];
    }
  }
  __syncthreads();

  // P5: amid = adj @ h1act -> [d][f] swizzled upper; stage w2T lower
  #pragma unroll
  for (int i=0;i<8;++i) acc[i] = (floatx4){0.f,0.f,0.f,0.f};
  #pragma unroll
  for (int ks=0;ks<4;++ks){
    int ca = ks*4 + q;
    short8 af = *(const short8*)(adjB + (m0+r)*128 + ((ca ^ (r&7)))*8);
    #pragma unroll
    for (int nt=0;nt<8;++nt){
      short8 bf = *(const short8*)(R1 + (nt*16+r)*128 + ((ca ^ (r&7)))*8);
      acc[nt] = MFMA(af, bf, acc[nt]);
    }
  }
  {
    u16 hv[32];
    #pragma unroll
    for (int nt=0;nt<8;++nt)
      #pragma unroll
      for (int rr=0;rr<4;++rr) hv[nt*4+rr] = f2b(acc[nt][rr]);
    __syncthreads();                        // adjB + h1T reads done
    #pragma unroll
    for (int rep=0;rep<32;++rep){           // w2T -> lower (overwrite adjB)
      int idx = rep*512 + t;
      int n = idx & 127, k = idx >> 7;
      WL[n*128 + (((k>>3) ^ (n&7)))*8 + (k&7)] = f2b(W2[idx]);
    }
    #pragma unroll
    for (int nt=0;nt<8;++nt){
      int ch = 2*nt + (r>>3);
      #pragma unroll
      for (int rr=0;rr<4;++rr){
        int d = m0 + q*4 + rr;
        R1[d*128 + (ch ^ (d&7))*8 + (r&7)] = hv[nt*4+rr];
      }
    }
  }
  __syncthreads();

  // P6: h2 = relu(amid @ W2 + b2) -> [d][f] -> hact
  #pragma unroll
  for (int i=0;i<8;++i) acc[i] = (floatx4){0.f,0.f,0.f,0.f};
  #pragma unroll
  for (int ks=0;ks<4;++ks){
    int ca = ks*4 + q;
    short8 af = *(const short8*)(R1 + (m0+r)*128 + ((ca ^ (r&7)))*8);
    #pragma unroll
    for (int nt=0;nt<8;++nt){
      short8 bf = *(const short8*)(WL + (nt*16+r)*128 + ((ca ^ (r&7)))*8);
      acc[nt] = MFMA(af, bf, acc[nt]);
    }
  }
  {
    u16 hv[32];
    #pragma unroll
    for (int nt=0;nt<8;++nt){
      float bb = b2[nt*16 + r];
      #pragma unroll
      for (int rr=0;rr<4;++rr) hv[nt*4+rr] = f2b(fmaxf(acc[nt][rr] + bb, 0.f));
    }
    __syncthreads();                        // amid reads done
    #pragma unroll
    for (int nt=0;nt<8;++nt){
      int f = nt*16 + r;
      #pragma unroll
      for (int rr=0;rr<4;++rr){
        int d = m0 + q*4 + rr;
        R1[d*128 + f] = hv[nt*4+rr];        // linear for vectorized copy-out
      }
    }
  }
  __syncthreads();
  u16* hg = hact + (size_t)g*KBIG;
  #pragma unroll
  for (int i=0;i<4;++i) ((int4*)hg)[t + i*512] = ((const int4*)R1)[t + i*512];
}

// ---- lin1: hact[256x16384]bf16 @ lin1_w[16384x512]fp32 (cast in staging).
//      256(M) x 64(N) x K=512/block, 32 k-slices, double-buffered LDS with
//      register prefetch (1 block/CU; global latency hidden behind compute).
__global__ __launch_bounds__(512) void gemm_lin1(
    const u16* __restrict__ A, const float* __restrict__ W, float* __restrict__ P)
{
  __shared__ u16 Al[2][256*64];    // 2 x 32 KB, 8 chunks/row XOR-swizzled
  __shared__ u16 Bl[2][64*64];     // 2 x 8 KB
  int t = threadIdx.x;
  int wave = t>>6, lane = t&63, r = lane&15, q = lane>>4;
  int n0 = blockIdx.x*64;
  int kbase = blockIdx.y*512;      // 32 slices x 512 K each
  floatx4 acc[2][4];
  #pragma unroll
  for (int i=0;i<2;++i)
    #pragma unroll
    for (int j=0;j<4;++j) acc[i][j] = (floatx4){0.f,0.f,0.f,0.f};

  int4   va[4];
  float4 wb[2];

  // prologue: load + stash iter 0
  #pragma unroll
  for (int p=0;p<4;++p){
    int idx = p*512 + t, row = idx >> 3, ch = idx & 7;
    va[p] = *(const int4*)(A + (size_t)row*KBIG + kbase + ch*8);
  }
  #pragma unroll
  for (int h=0;h<2;++h){
    int i = h*512 + t, k = i >> 4, n4 = i & 15;
    wb[h] = *(const float4*)(W + (size_t)(kbase + k)*MLP_HID + n0 + n4*4);
  }
  #pragma unroll
  for (int p=0;p<4;++p){
    int idx = p*512 + t, row = idx >> 3, ch = idx & 7;
    *(int4*)(&Al[0][row*64 + ((ch ^ (row&7)))*8]) = va[p];
  }
  #pragma unroll
  for (int h=0;h<2;++h){
    int i = h*512 + t, k = i >> 4, n4 = i & 15;
    float4 w = wb[h];
    #pragma unroll
    for (int j=0;j<4;++j){
      int n = n4*4 + j;
      Bl[0][n*64 + (((k>>3) ^ (n&7)))*8 + (k&7)] = f2b(j==0?w.x:j==1?w.y:j==2?w.z:w.w);
    }
  }

  for (int it=0; it<8; ++it){
    int cur = it & 1, nxt = cur ^ 1;
    if (it < 7){                    // prefetch next tile into regs (no wait)
      int kk = kbase + (it+1)*64;
      #pragma unroll
      for (int p=0;p<4;++p){
        int idx = p*512 + t, row = idx >> 3, ch = idx & 7;
        va[p] = *(const int4*)(A + (size_t)row*KBIG + kk + ch*8);
      }
      #pragma unroll
      for (int h=0;h<2;++h){
        int i = h*512 + t, k = i >> 4, n4 = i & 15;
        wb[h] = *(const float4*)(W + (size_t)(kk + k)*MLP_HID + n0 + n4*4);
      }
    }
    __syncthreads();                // LDS[cur] fully staged
    #pragma unroll
    for (int ks=0;ks<2;++ks){
      int ca = ks*4 + q;
      short8 a0 = *(const short8*)(&Al[cur][(wave*32      + r)*64 + ((ca ^ (r&7)))*8]);
      short8 a1 = *(const short8*)(&Al[cur][(wave*32 + 16 + r)*64 + ((ca ^ (r&7)))*8]);
      #pragma unroll
      for (int nt=0;nt<4;++nt){
        short8 b = *(const short8*)(&Bl[cur][(nt*16+r)*64 + ((ca ^ (r&7)))*8]);
        acc[0][nt] = MFMA(a0, b, acc[0][nt]);
        acc[1][nt] = MFMA(a1, b, acc[1][nt]);
      }
    }
    if (it < 7){                    // stash prefetched regs into LDS[nxt]
      #pragma unroll
      for (int p=0;p<4;++p){
        int idx = p*512 + t, row = idx >> 3, ch = idx & 7;
        *(int4*)(&Al[nxt][row*64 + ((ch ^ (row&7)))*8]) = va[p];
      }
      #pragma unroll
      for (int h=0;h<2;++h){
        int i = h*512 + t, k = i >> 4, n4 = i & 15;
        float4 w = wb[h];
        #pragma unroll
        for (int j=0;j<4;++j){
          int n = n4*4 + j;
          Bl[nxt][n*64 + (((k>>3) ^ (n&7)))*8 + (k&7)] = f2b(j==0?w.x:j==1?w.y:j==2?w.z:w.w);
        }
      }
    }
  }
  float* Pp = P + (size_t)blockIdx.y*131072;
  #pragma unroll
  for (int mm=0;mm<2;++mm)
    #pragma unroll
    for (int nt=0;nt<4;++nt)
      #pragma unroll
      for (int rr=0;rr<4;++rr)
        Pp[(size_t)(wave*32 + mm*16 + q*4 + rr)*MLP_HID + n0 + nt*16 + r] = acc[mm][nt][rr];
}

// ---- lin2: reduce 32 partial slices + b1, relu, then @ [512x10] + b2 ----
__global__ __launch_bounds__(256) void k_lin2(const float* __restrict__ P,
                                              const float* __restrict__ b1l,
                                              const float* __restrict__ w2,
                                              const float* __restrict__ b2,
                                              float* __restrict__ out){
  __shared__ float hs[MLP_HID];
  int g = blockIdx.x, t = threadIdx.x;
  #pragma unroll
  for (int c2=0;c2<2;++c2){
    int c = c2*256 + t;
    float s = b1l[c];
    #pragma unroll 8
    for (int sl=0;sl<KSLICES;++sl) s += P[(size_t)sl*131072 + (size_t)g*MLP_HID + c];
    hs[c] = fmaxf(s, 0.f);
  }
  __syncthreads();
  int wave = t >> 6, lane = t & 63;
  for (int j = wave; j < OUTDIM; j += 4){
    float p = 0.f;
    #pragma unroll
    for (int i=0;i<8;++i) p += hs[lane + i*64] * w2[(lane + i*64)*OUTDIM + j];
    #pragma unroll
    for (int off=32; off>0; off>>=1) p += __shfl_down(p, off);
    if (lane == 0) out[g*OUTDIM + j] = p + b2[j];
  }
}

extern "C" void kernel_launch(void* const* d_in, const int* in_sizes, int n_in,
                              void* d_out, int out_size, void* d_ws, size_t ws_size,
                              hipStream_t stream){
  const float* x   = (const float*)d_in[0];
  const int*   ei  = (const int*)d_in[1];
  const float* W1  = (const float*)d_in[3];
  const float* b1  = (const float*)d_in[4];
  const float* W2  = (const float*)d_in[5];
  const float* b2  = (const float*)d_in[6];
  const float* l1w = (const float*)d_in[7];
  const float* l1b = (const float*)d_in[8];
  const float* l2w = (const float*)d_in[9];
  const float* l2b = (const float*)d_in[10];
  float* out = (float*)d_out;

  char* ws = (char*)d_ws;
  u16*   hact = (u16*)  (ws + 0);          // 8 MB
  float* P    = (float*)(ws + 8388608);    // 16 MB partials (fully overwritten)

  k_gnn     <<<NGRAPH, 512, 0, stream>>>(x, ei, W1, W2, b1, b2, hact);
  gemm_lin1 <<<dim3(8, KSLICES), 512, 0, stream>>>(hact, l1w, P);
  k_lin2    <<<NGRAPH, 256, 0, stream>>>(P, l1b, l2w, l2b, out);
}

// Round 8
// 136.975 us; speedup vs baseline: 2.3581x; 1.0884x over previous
//
#include <hip/hip_runtime.h>
#include <hip/hip_bf16.h>
#include <hip/hip_fp16.h>

#define N_TOT   32768
#define NUMNODE 128
#define NGRAPH  256
#define EDGES   524288
#define HDIM    128
#define MLP_HID 512
#define OUTDIM  10
#define KBIG    16384   // NUMNODE*HDIM
#define KSLICES 64      // lin1 split-K slices (K=256 each)

typedef __attribute__((ext_vector_type(8))) short  short8;   // 8 x bf16 bits
typedef __attribute__((ext_vector_type(4))) float  floatx4;  // MFMA accumulator
typedef unsigned short u16;
typedef unsigned int   u32;

#define MFMA(a,b,c) __builtin_amdgcn_mfma_f32_16x16x32_bf16((a),(b),(c),0,0,0)

__device__ __forceinline__ u16 f2b(float f){
  union { __hip_bfloat16 h; u16 u; } cv; cv.h = __float2bfloat16(f); return cv.u;
}

// ==== fully self-contained per-graph GNN megakernel (R5-proven) ====
__global__ __launch_bounds__(512) void k_gnn(
    const float* __restrict__ x, const int* __restrict__ ei,
    const float* __restrict__ W1, const float* __restrict__ W2,
    const float* __restrict__ b1, const float* __restrict__ b2,
    u16* __restrict__ hact)
{
  __shared__ char smem[65536];
  u32*   adjC  = (u32*)smem;                // [128][64] packed u16 counts
  u16*   adjB  = (u16*)smem;                // [128][128] bf16 swizzled
  u16*   WL    = (u16*)smem;                // w2T home (after P5)
  float* dinvF = (float*)smem;              // 128 floats (transient)
  u16*   R1    = (u16*)(smem + 32768);      // w1T / hT / h1T / amid / out
  int g = blockIdx.x, t = threadIdx.x;
  int wave = t>>6, lane = t&63, r = lane&15, q = lane>>4;
  int m0 = wave*16;

  // P0: zero lower 32 KB; stage w1T (transposed bf16, swizzled) into upper
  #pragma unroll
  for (int i=0;i<4;++i) ((int4*)smem)[t + i*512] = make_int4(0,0,0,0);
  #pragma unroll
  for (int rep=0;rep<32;++rep){
    int idx = rep*512 + t;                  // = k*128 + n (W1 flat)
    int n = idx & 127, k = idx >> 7;
    R1[n*128 + (((k>>3) ^ (n&7)))*8 + (k&7)] = f2b(W1[idx]);
  }
  __syncthreads();

  // P1: scatter edge counts, packed 2 per u32
  #pragma unroll
  for (int k=0;k<4;++k){
    int e = g*2048 + k*512 + t;
    int s = ei[e] & 127;
    int d = ei[EDGES + e] & 127;
    atomicAdd(&adjC[d*64 + (s>>1)], 1u << (16*(s&1)));
  }
  __syncthreads();

  // P2a: own quarter-row counts -> regs; rowsum via shfl -> dinv
  int drow = t >> 2, c0q = (t & 3)*16, scol = (t & 3)*32;
  u32 cnts[16];
  float dinv_own;
  {
    u32 sum = 0;
    #pragma unroll
    for (int i=0;i<16;++i){
      cnts[i] = adjC[drow*64 + c0q + i];
      sum += (cnts[i] & 0xffffu) + (cnts[i] >> 16);
    }
    sum += __shfl_xor((int)sum, 1);
    sum += __shfl_xor((int)sum, 2);
    dinv_own = rsqrtf((float)sum + 1.0f);
  }
  __syncthreads();
  if ((t & 3) == 0) dinvF[drow] = dinv_own;
  __syncthreads();
  float vdst = dinvF[drow];
  float ds[32];
  #pragma unroll
  for (int i=0;i<8;++i)
    ((float4*)ds)[i] = *(const float4*)(dinvF + scol + i*4);
  __syncthreads();
  // P2d: normalize + self-loop diag, write adjB swizzled
  {
    float vals[32];
    #pragma unroll
    for (int i=0;i<16;++i){
      vals[2*i]   = (float)(cnts[i] & 0xffffu) * vdst * ds[2*i];
      vals[2*i+1] = (float)(cnts[i] >> 16)     * vdst * ds[2*i+1];
    }
    #pragma unroll
    for (int i=0;i<32;++i) if (drow == scol + i) vals[i] += vdst*vdst;
    #pragma unroll
    for (int cc=0;cc<4;++cc){
      int ch  = (scol >> 3) + cc;
      short8 o;
      #pragma unroll
      for (int j=0;j<8;++j) o[j] = (short)f2b(vals[cc*8 + j]);
      *(short8*)(adjB + drow*128 + (ch ^ (drow&7))*8) = o;
    }
  }
  // no barrier needed before P3 (P3 touches only upper LDS + global)

  // P3: GEMM1  h1 = x @ W1 -> hT [f][node] swizzled upper
  floatx4 acc[8];
  #pragma unroll
  for (int i=0;i<8;++i) acc[i] = (floatx4){0.f,0.f,0.f,0.f};
  {
    const float* xg = x + ((size_t)(g*128 + m0 + r))*HDIM;
    #pragma unroll
    for (int ks=0;ks<4;++ks){
      float4 a0 = *(const float4*)(xg + ks*32 + q*8);
      float4 a1 = *(const float4*)(xg + ks*32 + q*8 + 4);
      short8 af;
      af[0]=(short)f2b(a0.x); af[1]=(short)f2b(a0.y); af[2]=(short)f2b(a0.z); af[3]=(short)f2b(a0.w);
      af[4]=(short)f2b(a1.x); af[5]=(short)f2b(a1.y); af[6]=(short)f2b(a1.z); af[7]=(short)f2b(a1.w);
      #pragma unroll
      for (int nt=0;nt<8;++nt){
        short8 bf = *(const short8*)(R1 + (nt*16+r)*128 + (((ks*4+q) ^ (r&7)))*8);
        acc[nt] = MFMA(af, bf, acc[nt]);
      }
    }
  }
  __syncthreads();                          // w1T reads done; adjB writes done
  #pragma unroll
  for (int nt=0;nt<8;++nt){
    int f = nt*16 + r;
    int c = 2*wave + (q>>1);
    ushort4 o; o.x=f2b(acc[nt][0]); o.y=f2b(acc[nt][1]); o.z=f2b(acc[nt][2]); o.w=f2b(acc[nt][3]);
    *(ushort4*)(R1 + f*128 + (c ^ (f&7))*8 + (q&1)*4) = o;
  }
  __syncthreads();

  // P4: agg1 = adj @ h1 (+b1, relu) -> h1T [f][node] upper
  #pragma unroll
  for (int i=0;i<8;++i) acc[i] = (floatx4){0.f,0.f,0.f,0.f};
  #pragma unroll
  for (int ks=0;ks<4;++ks){
    int ca = ks*4 + q;
    short8 af = *(const short8*)(adjB + (m0+r)*128 + ((ca ^ (r&7)))*8);
    #pragma unroll
    for (int nt=0;nt<8;++nt){
      short8 bf = *(const short8*)(R1 + (nt*16+r)*128 + ((ca ^ (r&7)))*8);
      acc[nt] = MFMA(af, bf, acc[nt]);
    }
  }
  {
    ushort4 ho[8];
    #pragma unroll
    for (int nt=0;nt<8;++nt){
      float bb = b1[nt*16 + r];
      ho[nt].x = f2b(fmaxf(acc[nt][0] + bb, 0.f));
      ho[nt].y = f2b(fmaxf(acc[nt][1] + bb, 0.f));
      ho[nt].z = f2b(fmaxf(acc[nt][2] + bb, 0.f));
      ho[nt].w = f2b(fmaxf(acc[nt][3] + bb, 0.f));
    }
    __syncthreads();                        // hT reads done
    #pragma unroll
    for (int nt=0;nt<8;++nt){
      int f = nt*16 + r;
      int c = 2*wave + (q>>1);
      *(ushort4*)(R1 + f*128 + (c ^ (f&7))*8 + (q&1)*4) = ho[nt];
    }
  }
  __syncthreads();

  // P5: amid = adj @ h1act -> [d][f] swizzled upper; stage w2T lower
  #pragma unroll
  for (int i=0;i<8;++i) acc[i] = (floatx4){0.f,0.f,0.f,0.f};
  #pragma unroll
  for (int ks=0;ks<4;++ks){
    int ca = ks*4 + q;
    short8 af = *(const short8*)(adjB + (m0+r)*128 + ((ca ^ (r&7)))*8);
    #pragma unroll
    for (int nt=0;nt<8;++nt){
      short8 bf = *(const short8*)(R1 + (nt*16+r)*128 + ((ca ^ (r&7)))*8);
      acc[nt] = MFMA(af, bf, acc[nt]);
    }
  }
  {
    u16 hv[32];
    #pragma unroll
    for (int nt=0;nt<8;++nt)
      #pragma unroll
      for (int rr=0;rr<4;++rr) hv[nt*4+rr] = f2b(acc[nt][rr]);
    __syncthreads();                        // adjB + h1T reads done
    #pragma unroll
    for (int rep=0;rep<32;++rep){           // w2T -> lower (overwrite adjB)
      int idx = rep*512 + t;
      int n = idx & 127, k = idx >> 7;
      WL[n*128 + (((k>>3) ^ (n&7)))*8 + (k&7)] = f2b(W2[idx]);
    }
    #pragma unroll
    for (int nt=0;nt<8;++nt){
      int ch = 2*nt + (r>>3);
      #pragma unroll
      for (int rr=0;rr<4;++rr){
        int d = m0 + q*4 + rr;
        R1[d*128 + (ch ^ (d&7))*8 + (r&7)] = hv[nt*4+rr];
      }
    }
  }
  __syncthreads();

  // P6: h2 = relu(amid @ W2 + b2) -> [d][f] -> hact
  #pragma unroll
  for (int i=0;i<8;++i) acc[i] = (floatx4){0.f,0.f,0.f,0.f};
  #pragma unroll
  for (int ks=0;ks<4;++ks){
    int ca = ks*4 + q;
    short8 af = *(const short8*)(R1 + (m0+r)*128 + ((ca ^ (r&7)))*8);
    #pragma unroll
    for (int nt=0;nt<8;++nt){
      short8 bf = *(const short8*)(WL + (nt*16+r)*128 + ((ca ^ (r&7)))*8);
      acc[nt] = MFMA(af, bf, acc[nt]);
    }
  }
  {
    u16 hv[32];
    #pragma unroll
    for (int nt=0;nt<8;++nt){
      float bb = b2[nt*16 + r];
      #pragma unroll
      for (int rr=0;rr<4;++rr) hv[nt*4+rr] = f2b(fmaxf(acc[nt][rr] + bb, 0.f));
    }
    __syncthreads();                        // amid reads done
    #pragma unroll
    for (int nt=0;nt<8;++nt){
      int f = nt*16 + r;
      #pragma unroll
      for (int rr=0;rr<4;++rr){
        int d = m0 + q*4 + rr;
        R1[d*128 + f] = hv[nt*4+rr];        // linear for vectorized copy-out
      }
    }
  }
  __syncthreads();
  u16* hg = hact + (size_t)g*KBIG;
  #pragma unroll
  for (int i=0;i<4;++i) ((int4*)hg)[t + i*512] = ((const int4*)R1)[t + i*512];
}

// ---- lin1: hact[256x16384]bf16 @ lin1_w[16384x512]fp32 (cast in staging).
//      R5-proven: 256(M) x 64(N) x BK=64, 64 k-slices, grid 8x64 = 2 blocks/CU.
//      fp16 partials (halved P traffic vs R5).
__global__ __launch_bounds__(512) void gemm_lin1(
    const u16* __restrict__ A, const float* __restrict__ W, __half* __restrict__ P)
{
  __shared__ u16 Al[256*64];     // 32 KB: row m, 8 chunks XOR-swizzled
  __shared__ u16 Bl[64*64];      // 8 KB:  row n, 8 chunks XOR-swizzled
  int t = threadIdx.x;
  int wave = t>>6, lane = t&63, r = lane&15, q = lane>>4;
  int n0 = blockIdx.x*64;
  int kbase = blockIdx.y*256;    // 64 slices x 256 K each
  floatx4 acc[2][4];
  #pragma unroll
  for (int i=0;i<2;++i)
    #pragma unroll
    for (int j=0;j<4;++j) acc[i][j] = (floatx4){0.f,0.f,0.f,0.f};

  for (int it=0; it<4; ++it){
    __syncthreads();
    int kk = kbase + it*64;
    #pragma unroll
    for (int p=0;p<4;++p){                  // A: 256 rows x 64 k
      int idx = p*512 + t;
      int row = idx >> 3, ch = idx & 7;
      int4 va = *(const int4*)(A + (size_t)row*KBIG + kk + ch*8);
      *(int4*)(Al + row*64 + ((ch ^ (row&7)))*8) = va;
    }
    #pragma unroll
    for (int h=0;h<2;++h){                  // B: W[kk..kk+63][n0..n0+63] -> Bl[n][k]
      int i = h*512 + t;
      int k = i >> 4, n4 = i & 15;
      float4 w = *(const float4*)(W + (size_t)(kk + k)*MLP_HID + n0 + n4*4);
      #pragma unroll
      for (int j=0;j<4;++j){
        int n = n4*4 + j;
        Bl[n*64 + (((k>>3) ^ (n&7)))*8 + (k&7)] = f2b(j==0?w.x:j==1?w.y:j==2?w.z:w.w);
      }
    }
    __syncthreads();
    #pragma unroll
    for (int ks=0;ks<2;++ks){
      int ca = ks*4 + q;
      short8 a0 = *(const short8*)(Al + (wave*32      + r)*64 + ((ca ^ (r&7)))*8);
      short8 a1 = *(const short8*)(Al + (wave*32 + 16 + r)*64 + ((ca ^ (r&7)))*8);
      #pragma unroll
      for (int nt=0;nt<4;++nt){
        short8 b = *(const short8*)(Bl + (nt*16+r)*64 + ((ca ^ (r&7)))*8);
        acc[0][nt] = MFMA(a0, b, acc[0][nt]);
        acc[1][nt] = MFMA(a1, b, acc[1][nt]);
      }
    }
  }
  __half* Pp = P + (size_t)blockIdx.y*131072;
  #pragma unroll
  for (int mm=0;mm<2;++mm)
    #pragma unroll
    for (int nt=0;nt<4;++nt)
      #pragma unroll
      for (int rr=0;rr<4;++rr)
        Pp[(size_t)(wave*32 + mm*16 + q*4 + rr)*MLP_HID + n0 + nt*16 + r] =
          __float2half(acc[mm][nt][rr]);
}

// ---- lin2: reduce 64 fp16 partial slices + b1, relu, then @ [512x10] + b2 ----
__global__ __launch_bounds__(256) void k_lin2(const __half* __restrict__ P,
                                              const float* __restrict__ b1l,
                                              const float* __restrict__ w2,
                                              const float* __restrict__ b2,
                                              float* __restrict__ out){
  __shared__ float hs[MLP_HID];
  int g = blockIdx.x, t = threadIdx.x;
  {
    // each thread owns 2 adjacent columns via __half2 loads
    int c = t*2;
    float s0 = b1l[c], s1 = b1l[c+1];
    #pragma unroll 8
    for (int sl=0;sl<KSLICES;++sl){
      __half2 v = *(const __half2*)(P + (size_t)sl*131072 + (size_t)g*MLP_HID + c);
      float2 f = __half22float2(v);
      s0 += f.x; s1 += f.y;
    }
    hs[c]   = fmaxf(s0, 0.f);
    hs[c+1] = fmaxf(s1, 0.f);
  }
  __syncthreads();
  int wave = t >> 6, lane = t & 63;
  for (int j = wave; j < OUTDIM; j += 4){
    float p = 0.f;
    #pragma unroll
    for (int i=0;i<8;++i) p += hs[lane + i*64] * w2[(lane + i*64)*OUTDIM + j];
    #pragma unroll
    for (int off=32; off>0; off>>=1) p += __shfl_down(p, off);
    if (lane == 0) out[g*OUTDIM + j] = p + b2[j];
  }
}

extern "C" void kernel_launch(void* const* d_in, const int* in_sizes, int n_in,
                              void* d_out, int out_size, void* d_ws, size_t ws_size,
                              hipStream_t stream){
  const float* x   = (const float*)d_in[0];
  const int*   ei  = (const int*)d_in[1];
  const float* W1  = (const float*)d_in[3];
  const float* b1  = (const float*)d_in[4];
  const float* W2  = (const float*)d_in[5];
  const float* b2  = (const float*)d_in[6];
  const float* l1w = (const float*)d_in[7];
  const float* l1b = (const float*)d_in[8];
  const float* l2w = (const float*)d_in[9];
  const float* l2b = (const float*)d_in[10];
  float* out = (float*)d_out;

  char* ws = (char*)d_ws;
  u16*    hact = (u16*)   (ws + 0);          // 8 MB
  __half* P    = (__half*)(ws + 8388608);    // 16 MB fp16 partials (fully overwritten)

  k_gnn     <<<NGRAPH, 512, 0, stream>>>(x, ei, W1, W2, b1, b2, hact);
  gemm_lin1 <<<dim3(8, KSLICES), 512, 0, stream>>>(hact, l1w, P);
  k_lin2    <<<NGRAPH, 256, 0, stream>>>(P, l1b, l2w, l2b, out);
}

// Round 9
// 134.704 us; speedup vs baseline: 2.3979x; 1.0169x over previous
//
#include <hip/hip_runtime.h>
#include <hip/hip_bf16.h>
#include <hip/hip_fp16.h>

#define N_TOT   32768
#define NUMNODE 128
#define NGRAPH  256
#define EDGES   524288
#define HDIM    128
#define MLP_HID 512
#define OUTDIM  10
#define KBIG    16384   // NUMNODE*HDIM
#define KSLICES 64      // lin1 split-K slices (K=256 each)

typedef __attribute__((ext_vector_type(8))) short  short8;   // 8 x bf16 bits
typedef __attribute__((ext_vector_type(4))) float  floatx4;  // MFMA accumulator
typedef unsigned short u16;
typedef unsigned int   u32;

#define MFMA(a,b,c) __builtin_amdgcn_mfma_f32_16x16x32_bf16((a),(b),(c),0,0,0)

__device__ __forceinline__ u16 f2b(float f){
  union { __hip_bfloat16 h; u16 u; } cv; cv.h = __float2bfloat16(f); return cv.u;
}

// ==== fully self-contained per-graph GNN megakernel ====
// R8 structure + global-load hoisting: ei and x issued at kernel entry so
// their HBM latency overlaps P0 (LDS zero + W1 stage) and P1/P2.
__global__ __launch_bounds__(512) void k_gnn(
    const float* __restrict__ x, const int* __restrict__ ei,
    const float* __restrict__ W1, const float* __restrict__ W2,
    const float* __restrict__ b1, const float* __restrict__ b2,
    u16* __restrict__ hact)
{
  __shared__ char smem[65536];
  u32*   adjC  = (u32*)smem;                // [128][64] packed u16 counts
  u16*   adjB  = (u16*)smem;                // [128][128] bf16 swizzled
  u16*   WL    = (u16*)smem;                // w2T home (after P5)
  float* dinvF = (float*)smem;              // 128 floats (transient)
  u16*   R1    = (u16*)(smem + 32768);      // w1T / hT / h1T / amid / out
  int g = blockIdx.x, t = threadIdx.x;
  int wave = t>>6, lane = t&63, r = lane&15, q = lane>>4;
  int m0 = wave*16;

  // ---- hoisted global loads: x fragment rows + this thread's 4 edges ----
  float4 xv[8];
  {
    const float* xg = x + ((size_t)(g*128 + m0 + r))*HDIM;
    #pragma unroll
    for (int ks=0;ks<4;++ks){
      xv[2*ks]   = *(const float4*)(xg + ks*32 + q*8);
      xv[2*ks+1] = *(const float4*)(xg + ks*32 + q*8 + 4);
    }
  }
  int es[4], ed[4];
  #pragma unroll
  for (int k=0;k<4;++k){
    int e = g*2048 + k*512 + t;
    es[k] = ei[e];
    ed[k] = ei[EDGES + e];
  }

  // P0: zero lower 32 KB; stage w1T (transposed bf16, swizzled) into upper
  #pragma unroll
  for (int i=0;i<4;++i) ((int4*)smem)[t + i*512] = make_int4(0,0,0,0);
  #pragma unroll
  for (int rep=0;rep<32;++rep){
    int idx = rep*512 + t;                  // = k*128 + n (W1 flat)
    int n = idx & 127, k = idx >> 7;
    R1[n*128 + (((k>>3) ^ (n&7)))*8 + (k&7)] = f2b(W1[idx]);
  }
  __syncthreads();

  // P1: scatter edge counts from hoisted regs, packed 2 per u32
  #pragma unroll
  for (int k=0;k<4;++k){
    int s = es[k] & 127;
    int d = ed[k] & 127;
    atomicAdd(&adjC[d*64 + (s>>1)], 1u << (16*(s&1)));
  }
  __syncthreads();

  // P2a: own quarter-row counts -> regs; rowsum via shfl -> dinv
  int drow = t >> 2, c0q = (t & 3)*16, scol = (t & 3)*32;
  u32 cnts[16];
  float dinv_own;
  {
    u32 sum = 0;
    #pragma unroll
    for (int i=0;i<16;++i){
      cnts[i] = adjC[drow*64 + c0q + i];
      sum += (cnts[i] & 0xffffu) + (cnts[i] >> 16);
    }
    sum += __shfl_xor((int)sum, 1);
    sum += __shfl_xor((int)sum, 2);
    dinv_own = rsqrtf((float)sum + 1.0f);
  }
  __syncthreads();
  if ((t & 3) == 0) dinvF[drow] = dinv_own;
  __syncthreads();
  float vdst = dinvF[drow];
  float ds[32];
  #pragma unroll
  for (int i=0;i<8;++i)
    ((float4*)ds)[i] = *(const float4*)(dinvF + scol + i*4);
  __syncthreads();
  // P2d: normalize + self-loop diag, write adjB swizzled
  {
    float vals[32];
    #pragma unroll
    for (int i=0;i<16;++i){
      vals[2*i]   = (float)(cnts[i] & 0xffffu) * vdst * ds[2*i];
      vals[2*i+1] = (float)(cnts[i] >> 16)     * vdst * ds[2*i+1];
    }
    #pragma unroll
    for (int i=0;i<32;++i) if (drow == scol + i) vals[i] += vdst*vdst;
    #pragma unroll
    for (int cc=0;cc<4;++cc){
      int ch  = (scol >> 3) + cc;
      short8 o;
      #pragma unroll
      for (int j=0;j<8;++j) o[j] = (short)f2b(vals[cc*8 + j]);
      *(short8*)(adjB + drow*128 + (ch ^ (drow&7))*8) = o;
    }
  }
  // no barrier needed before P3 (P3 touches only upper LDS + regs)

  // P3: GEMM1  h1 = x @ W1 -> hT [f][node] swizzled upper
  floatx4 acc[8];
  #pragma unroll
  for (int i=0;i<8;++i) acc[i] = (floatx4){0.f,0.f,0.f,0.f};
  #pragma unroll
  for (int ks=0;ks<4;++ks){
    float4 a0 = xv[2*ks], a1 = xv[2*ks+1];
    short8 af;
    af[0]=(short)f2b(a0.x); af[1]=(short)f2b(a0.y); af[2]=(short)f2b(a0.z); af[3]=(short)f2b(a0.w);
    af[4]=(short)f2b(a1.x); af[5]=(short)f2b(a1.y); af[6]=(short)f2b(a1.z); af[7]=(short)f2b(a1.w);
    #pragma unroll
    for (int nt=0;nt<8;++nt){
      short8 bf = *(const short8*)(R1 + (nt*16+r)*128 + (((ks*4+q) ^ (r&7)))*8);
      acc[nt] = MFMA(af, bf, acc[nt]);
    }
  }
  __syncthreads();                          // w1T reads done; adjB writes done
  #pragma unroll
  for (int nt=0;nt<8;++nt){
    int f = nt*16 + r;
    int c = 2*wave + (q>>1);
    ushort4 o; o.x=f2b(acc[nt][0]); o.y=f2b(acc[nt][1]); o.z=f2b(acc[nt][2]); o.w=f2b(acc[nt][3]);
    *(ushort4*)(R1 + f*128 + (c ^ (f&7))*8 + (q&1)*4) = o;
  }
  __syncthreads();

  // P4: agg1 = adj @ h1 (+b1, relu) -> h1T [f][node] upper
  #pragma unroll
  for (int i=0;i<8;++i) acc[i] = (floatx4){0.f,0.f,0.f,0.f};
  #pragma unroll
  for (int ks=0;ks<4;++ks){
    int ca = ks*4 + q;
    short8 af = *(const short8*)(adjB + (m0+r)*128 + ((ca ^ (r&7)))*8);
    #pragma unroll
    for (int nt=0;nt<8;++nt){
      short8 bf = *(const short8*)(R1 + (nt*16+r)*128 + ((ca ^ (r&7)))*8);
      acc[nt] = MFMA(af, bf, acc[nt]);
    }
  }
  {
    ushort4 ho[8];
    #pragma unroll
    for (int nt=0;nt<8;++nt){
      float bb = b1[nt*16 + r];
      ho[nt].x = f2b(fmaxf(acc[nt][0] + bb, 0.f));
      ho[nt].y = f2b(fmaxf(acc[nt][1] + bb, 0.f));
      ho[nt].z = f2b(fmaxf(acc[nt][2] + bb, 0.f));
      ho[nt].w = f2b(fmaxf(acc[nt][3] + bb, 0.f));
    }
    __syncthreads();                        // hT reads done
    #pragma unroll
    for (int nt=0;nt<8;++nt){
      int f = nt*16 + r;
      int c = 2*wave + (q>>1);
      *(ushort4*)(R1 + f*128 + (c ^ (f&7))*8 + (q&1)*4) = ho[nt];
    }
  }
  __syncthreads();

  // P5: amid = adj @ h1act -> [d][f] swizzled upper; stage w2T lower
  #pragma unroll
  for (int i=0;i<8;++i) acc[i] = (floatx4){0.f,0.f,0.f,0.f};
  #pragma unroll
  for (int ks=0;ks<4;++ks){
    int ca = ks*4 + q;
    short8 af = *(const short8*)(adjB + (m0+r)*128 + ((ca ^ (r&7)))*8);
    #pragma unroll
    for (int nt=0;nt<8;++nt){
      short8 bf = *(const short8*)(R1 + (nt*16+r)*128 + ((ca ^ (r&7)))*8);
      acc[nt] = MFMA(af, bf, acc[nt]);
    }
  }
  {
    u16 hv[32];
    #pragma unroll
    for (int nt=0;nt<8;++nt)
      #pragma unroll
      for (int rr=0;rr<4;++rr) hv[nt*4+rr] = f2b(acc[nt][rr]);
    __syncthreads();                        // adjB + h1T reads done
    #pragma unroll
    for (int rep=0;rep<32;++rep){           // w2T -> lower (overwrite adjB)
      int idx = rep*512 + t;
      int n = idx & 127, k = idx >> 7;
      WL[n*128 + (((k>>3) ^ (n&7)))*8 + (k&7)] = f2b(W2[idx]);
    }
    #pragma unroll
    for (int nt=0;nt<8;++nt){
      int ch = 2*nt + (r>>3);
      #pragma unroll
      for (int rr=0;rr<4;++rr){
        int d = m0 + q*4 + rr;
        R1[d*128 + (ch ^ (d&7))*8 + (r&7)] = hv[nt*4+rr];
      }
    }
  }
  __syncthreads();

  // P6: h2 = relu(amid @ W2 + b2) -> [d][f] -> hact
  #pragma unroll
  for (int i=0;i<8;++i) acc[i] = (floatx4){0.f,0.f,0.f,0.f};
  #pragma unroll
  for (int ks=0;ks<4;++ks){
    int ca = ks*4 + q;
    short8 af = *(const short8*)(R1 + (m0+r)*128 + ((ca ^ (r&7)))*8);
    #pragma unroll
    for (int nt=0;nt<8;++nt){
      short8 bf = *(const short8*)(WL + (nt*16+r)*128 + ((ca ^ (r&7)))*8);
      acc[nt] = MFMA(af, bf, acc[nt]);
    }
  }
  {
    u16 hv[32];
    #pragma unroll
    for (int nt=0;nt<8;++nt){
      float bb = b2[nt*16 + r];
      #pragma unroll
      for (int rr=0;rr<4;++rr) hv[nt*4+rr] = f2b(fmaxf(acc[nt][rr] + bb, 0.f));
    }
    __syncthreads();                        // amid reads done
    #pragma unroll
    for (int nt=0;nt<8;++nt){
      int f = nt*16 + r;
      #pragma unroll
      for (int rr=0;rr<4;++rr){
        int d = m0 + q*4 + rr;
        R1[d*128 + f] = hv[nt*4+rr];        // linear for vectorized copy-out
      }
    }
  }
  __syncthreads();
  u16* hg = hact + (size_t)g*KBIG;
  #pragma unroll
  for (int i=0;i<4;++i) ((int4*)hg)[t + i*512] = ((const int4*)R1)[t + i*512];
}

// ---- lin1: hact[256x16384]bf16 @ lin1_w[16384x512]fp32 (cast in staging).
//      R8-proven: 256(M) x 64(N) x BK=64, 64 k-slices, grid 8x64 = 2 blocks/CU,
//      fp16 partials. FROZEN.
__global__ __launch_bounds__(512) void gemm_lin1(
    const u16* __restrict__ A, const float* __restrict__ W, __half* __restrict__ P)
{
  __shared__ u16 Al[256*64];     // 32 KB: row m, 8 chunks XOR-swizzled
  __shared__ u16 Bl[64*64];      // 8 KB:  row n, 8 chunks XOR-swizzled
  int t = threadIdx.x;
  int wave = t>>6, lane = t&63, r = lane&15, q = lane>>4;
  int n0 = blockIdx.x*64;
  int kbase = blockIdx.y*256;    // 64 slices x 256 K each
  floatx4 acc[2][4];
  #pragma unroll
  for (int i=0;i<2;++i)
    #pragma unroll
    for (int j=0;j<4;++j) acc[i][j] = (floatx4){0.f,0.f,0.f,0.f};

  for (int it=0; it<4; ++it){
    __syncthreads();
    int kk = kbase + it*64;
    #pragma unroll
    for (int p=0;p<4;++p){                  // A: 256 rows x 64 k
      int idx = p*512 + t;
      int row = idx >> 3, ch = idx & 7;
      int4 va = *(const int4*)(A + (size_t)row*KBIG + kk + ch*8);
      *(int4*)(Al + row*64 + ((ch ^ (row&7)))*8) = va;
    }
    #pragma unroll
    for (int h=0;h<2;++h){                  // B: W[kk..kk+63][n0..n0+63] -> Bl[n][k]
      int i = h*512 + t;
      int k = i >> 4, n4 = i & 15;
      float4 w = *(const float4*)(W + (size_t)(kk + k)*MLP_HID + n0 + n4*4);
      #pragma unroll
      for (int j=0;j<4;++j){
        int n = n4*4 + j;
        Bl[n*64 + (((k>>3) ^ (n&7)))*8 + (k&7)] = f2b(j==0?w.x:j==1?w.y:j==2?w.z:w.w);
      }
    }
    __syncthreads();
    #pragma unroll
    for (int ks=0;ks<2;++ks){
      int ca = ks*4 + q;
      short8 a0 = *(const short8*)(Al + (wave*32      + r)*64 + ((ca ^ (r&7)))*8);
      short8 a1 = *(const short8*)(Al + (wave*32 + 16 + r)*64 + ((ca ^ (r&7)))*8);
      #pragma unroll
      for (int nt=0;nt<4;++nt){
        short8 b = *(const short8*)(Bl + (nt*16+r)*64 + ((ca ^ (r&7)))*8);
        acc[0][nt] = MFMA(a0, b, acc[0][nt]);
        acc[1][nt] = MFMA(a1, b, acc[1][nt]);
      }
    }
  }
  __half* Pp = P + (size_t)blockIdx.y*131072;
  #pragma unroll
  for (int mm=0;mm<2;++mm)
    #pragma unroll
    for (int nt=0;nt<4;++nt)
      #pragma unroll
      for (int rr=0;rr<4;++rr)
        Pp[(size_t)(wave*32 + mm*16 + q*4 + rr)*MLP_HID + n0 + nt*16 + r] =
          __float2half(acc[mm][nt][rr]);
}

// ---- lin2: reduce 64 fp16 partial slices + b1, relu, then @ [512x10] + b2 ----
// 4 thread-groups x 16 slices, int4 (8-half) loads, LDS partial reduce.
__global__ __launch_bounds__(256) void k_lin2(const __half* __restrict__ P,
                                              const float* __restrict__ b1l,
                                              const float* __restrict__ w2,
                                              const float* __restrict__ b2,
                                              float* __restrict__ out){
  __shared__ float pf[4][MLP_HID];   // 8 KB group partials
  __shared__ float hs[MLP_HID];
  int g = blockIdx.x, t = threadIdx.x;
  int grp = t >> 6, ln = t & 63;
  int c0 = ln*8;
  float s[8];
  #pragma unroll
  for (int j=0;j<8;++j) s[j] = 0.f;
  #pragma unroll
  for (int i=0;i<16;++i){
    int sl = grp + i*4;
    int4 v = *(const int4*)(P + (size_t)sl*131072 + (size_t)g*MLP_HID + c0);
    __half2* h2 = (__half2*)&v;      // 4 x half2
    #pragma unroll
    for (int j=0;j<4;++j){
      float2 f = __half22float2(h2[j]);
      s[2*j] += f.x; s[2*j+1] += f.y;
    }
  }
  *(float4*)&pf[grp][c0]     = make_float4(s[0],s[1],s[2],s[3]);
  *(float4*)&pf[grp][c0 + 4] = make_float4(s[4],s[5],s[6],s[7]);
  __syncthreads();
  {
    int c = t*2;
    float a0 = b1l[c]   + pf[0][c]   + pf[1][c]   + pf[2][c]   + pf[3][c];
    float a1 = b1l[c+1] + pf[0][c+1] + pf[1][c+1] + pf[2][c+1] + pf[3][c+1];
    hs[c]   = fmaxf(a0, 0.f);
    hs[c+1] = fmaxf(a1, 0.f);
  }
  __syncthreads();
  int wave = t >> 6, lane = t & 63;
  for (int j = wave; j < OUTDIM; j += 4){
    float p = 0.f;
    #pragma unroll
    for (int i=0;i<8;++i) p += hs[lane + i*64] * w2[(lane + i*64)*OUTDIM + j];
    #pragma unroll
    for (int off=32; off>0; off>>=1) p += __shfl_down(p, off);
    if (lane == 0) out[g*OUTDIM + j] = p + b2[j];
  }
}

extern "C" void kernel_launch(void* const* d_in, const int* in_sizes, int n_in,
                              void* d_out, int out_size, void* d_ws, size_t ws_size,
                              hipStream_t stream){
  const float* x   = (const float*)d_in[0];
  const int*   ei  = (const int*)d_in[1];
  const float* W1  = (const float*)d_in[3];
  const float* b1  = (const float*)d_in[4];
  const float* W2  = (const float*)d_in[5];
  const float* b2  = (const float*)d_in[6];
  const float* l1w = (const float*)d_in[7];
  const float* l1b = (const float*)d_in[8];
  const float* l2w = (const float*)d_in[9];
  const float* l2b = (const float*)d_in[10];
  float* out = (float*)d_out;

  char* ws = (char*)d_ws;
  u16*    hact = (u16*)   (ws + 0);          // 8 MB
  __half* P    = (__half*)(ws + 8388608);    // 16 MB fp16 partials (fully overwritten)

  k_gnn     <<<NGRAPH, 512, 0, stream>>>(x, ei, W1, W2, b1, b2, hact);
  gemm_lin1 <<<dim3(8, KSLICES), 512, 0, stream>>>(hact, l1w, P);
  k_lin2    <<<NGRAPH, 256, 0, stream>>>(P, l1b, l2w, l2b, out);
}